// Round 1
// baseline (262.503 us; speedup 1.0000x reference)
//
#include <hip/hip_runtime.h>
#include <math.h>

// Static problem config
#define NB     16      // graphs
#define NN     64      // nodes per graph
#define KK     4       // subgraph size
#define PP     6       // (K-1)!
#define HH     64      // hid dim
#define NSUB   2048    // total subgraphs
#define NC0    65      // c0 in [0,64]
#define NMASK  16      // 2^K
#define NCOMBO (NC0*NMASK)

// Workspace layout (float element offsets)
#define OFF_ROWSUM 0                 // 16*64            = 1024
#define OFF_LABW   1024              // 4*6*64           = 1536
#define OFF_W1SUM  2560              // 64
#define OFF_BASEW  2624              // 5*64             = 320
#define OFF_SW     2944              // 1040*64          = 66560
#define OFF_GKEYS  69504             // 16*64 (as uint)  = 1024
// total 70528 floats = 282112 bytes

static __device__ inline float selu_f(float x) {
    const float alpha = 1.6732632423543772f;
    const float scale = 1.0507009873554805f;
    return x > 0.0f ? scale * x : scale * alpha * expm1f(x);
}
// order-preserving float->uint encoding for atomicMax-based segment max
static __device__ inline unsigned enc_f(float x) {
    unsigned b = __float_as_uint(x);
    return (b & 0x80000000u) ? ~b : (b | 0x80000000u);
}
static __device__ inline float dec_f(unsigned k) {
    unsigned b = (k & 0x80000000u) ? (k & 0x7FFFFFFFu) : ~k;
    return __uint_as_float(b);
}

// ---------------- Kernel A: rowsums + small tables + Gkeys init ----------------
__global__ __launch_bounds__(64) void k_prep(
    const float* __restrict__ adj, const float* __restrict__ idemb,
    const float* __restrict__ id_w, const float* __restrict__ set1_w,
    const float* __restrict__ set1_b, float* __restrict__ ws)
{
    const int t = threadIdx.x;            // 0..63
    const int blk = blockIdx.x;           // 0..16
    if (blk < NB) {
        // rowsum[blk][t] = sum_j adj[blk, t, j]  (exact: adj is 0/1)
        const float4* row = reinterpret_cast<const float4*>(adj + (blk*NN + t)*NN);
        float s = 0.f;
        #pragma unroll
        for (int k = 0; k < 16; ++k) { float4 v = row[k]; s += v.x + v.y + v.z + v.w; }
        ws[OFF_ROWSUM + blk*NN + t] = s;
        return;
    }
    // blk == NB: tables; t = output channel h'
    const int ap[4][6] = {{0,0,0,0,0,0},{1,1,2,2,3,3},{2,3,1,3,1,2},{3,2,3,1,2,1}};
    float* labW  = ws + OFF_LABW;
    float* w1sum = ws + OFF_W1SUM;
    float* baseW = ws + OFF_BASEW;
    unsigned* gk = reinterpret_cast<unsigned*>(ws) + OFF_GKEYS;

    { // w1sum[h'] = sum_h id_w[h][h']   (ones-row through id_w)
        float s = 0.f;
        for (int h = 0; h < HH; ++h) s += id_w[h*HH + t];
        w1sum[t] = s;
    }
    // labW[j][p][h'] = (lab[j,p,:] @ id_w)[h'],  lab[j,p,h] = idemb[ap[j][p]][h]*(j+1)*1000
    for (int j = 0; j < KK; ++j) {
        const float sc = (float)(j+1) * 1000.0f;
        for (int p = 0; p < PP; ++p) {
            const float* er = idemb + ap[j][p]*HH;
            float s = 0.f;
            for (int h = 0; h < HH; ++h) s += (er[h] * sc) * id_w[h*HH + t];
            labW[(j*PP + p)*HH + t] = s;
        }
    }
    // labsum[j][h] = sum_p lab[j,p,h]
    __shared__ float lsum[KK][HH];
    for (int j = 0; j < KK; ++j) {
        const float sc = (float)(j+1) * 1000.0f;
        float s = 0.f;
        for (int p = 0; p < PP; ++p) s += idemb[ap[j][p]*HH + t];
        lsum[j][t] = s * sc;
    }
    __syncthreads();
    // baseW[0] = (6*ones) @ set1_w + set1_b ; baseW[1+j] = labsum[j] @ set1_w + set1_b
    {
        float cs = 0.f;
        for (int hp = 0; hp < HH; ++hp) cs += set1_w[hp*HH + t];
        baseW[t] = 6.0f * cs + set1_b[t];
        for (int j = 0; j < KK; ++j) {
            float d = 0.f;
            for (int hp = 0; hp < HH; ++hp) d += lsum[j][hp] * set1_w[hp*HH + t];
            baseW[(1+j)*HH + t] = d + set1_b[t];
        }
    }
    for (int i = t; i < NB*HH; i += 64) gk[i] = 0u;  // 0 = smallest key
}

// ---------------- Kernel B: SW[c0,mask,:] table (1040 x 64) ----------------
__global__ __launch_bounds__(64) void k_table(
    const float* __restrict__ id_b, const float* __restrict__ set1_w,
    float* __restrict__ ws)
{
    const int c0   = blockIdx.x >> 4;
    const int mask = blockIdx.x & 15;
    const int t = threadIdx.x;
    const float* labW  = ws + OFF_LABW;
    const float* w1sum = ws + OFF_W1SUM;
    const float fc0 = (float)c0;
    float acc = 0.f;
    #pragma unroll
    for (int p = 0; p < PP; ++p) {
        float arg = fc0 * w1sum[t] + id_b[t];
        #pragma unroll
        for (int j = 0; j < KK; ++j)
            if ((mask >> j) & 1) arg += labW[(j*PP + p)*HH + t];
        acc += selu_f(arg);
    }
    __shared__ float S[HH];
    S[t] = acc;
    __syncthreads();
    float o = 0.f;
    #pragma unroll
    for (int hp = 0; hp < HH; ++hp) o += S[hp] * set1_w[hp*HH + t];
    ws[OFF_SW + blockIdx.x*HH + t] = o;
}

// ---------------- Kernel C: main per-subgraph pass ----------------
__global__ __launch_bounds__(256) void k_main(
    const float* __restrict__ adj, const int* __restrict__ subgs,
    const float* __restrict__ set2_w, const float* __restrict__ set2_b,
    float* __restrict__ ws)
{
    const int s = blockIdx.x;
    const int b = s >> 7;                 // 128 subgraphs per graph
    __shared__ int sub[KK];
    __shared__ float gpart[4][HH];
    if (threadIdx.x < KK) sub[threadIdx.x] = subgs[s*KK + threadIdx.x];
    __syncthreads();
    const int w = threadIdx.x >> 6, h = threadIdx.x & 63;
    const int s0 = sub[0], s1 = sub[1], s2 = sub[2], s3 = sub[3];
    const float* adjb = adj + b*NN*NN;
    const float* rs   = ws + OFF_ROWSUM + b*NN;
    const float* SW   = ws + OFF_SW;
    const float* baseW= ws + OFF_BASEW;
    float facc = 0.f;
    #pragma unroll 4
    for (int it = 0; it < 16; ++it) {
        const int i = w*16 + it;
        const float* arow = adjb + i*NN;
        const float a0 = arow[s0], a1 = arow[s1], a2 = arow[s2], a3 = arow[s3];
        const float c0f = rs[i] - (a0 + a1 + a2 + a3);
        const int ic0 = (int)(c0f + 0.5f);           // exact small integer
        const int mask = (a0 != 0.f ? 1 : 0) | (a1 != 0.f ? 2 : 0)
                       | (a2 != 0.f ? 4 : 0) | (a3 != 0.f ? 8 : 0);
        const int var = (i==s0) ? 1 : (i==s1) ? 2 : (i==s2) ? 3 : (i==s3) ? 4 : 0;
        const float val = SW[(ic0*NMASK + mask)*HH + h] + baseW[var*HH + h];
        facc += selu_f(val);
    }
    gpart[w][h] = facc;
    __syncthreads();
    if (w == 0) {
        float gsum = gpart[0][h] + gpart[1][h] + gpart[2][h] + gpart[3][h];
        // broadcast gsum across lanes via shuffles (no LDS RAW hazard)
        float o = set2_b[h];
        #pragma unroll
        for (int hp = 0; hp < HH; ++hp)
            o += __shfl(gsum, hp, 64) * set2_w[hp*HH + h];
        const float gq = selu_f(o);
        unsigned* gk = reinterpret_cast<unsigned*>(ws) + OFF_GKEYS;
        atomicMax(gk + b*HH + h, enc_f(gq));
    }
}

// ---------------- Kernel D: head (16 rows, 4 residual MLP blocks, out proj) ----------------
__global__ __launch_bounds__(1024) void k_head(
    const float* __restrict__ reg_w1, const float* __restrict__ reg_b1,
    const float* __restrict__ reg_w2, const float* __restrict__ reg_b2,
    const float* __restrict__ reg_ln_g, const float* __restrict__ reg_ln_b,
    const float* __restrict__ out_w, const float* __restrict__ out_b,
    const float* __restrict__ ws, float* __restrict__ out)
{
    const int r = threadIdx.x >> 6, h = threadIdx.x & 63;   // wave per graph row
    const unsigned* gk = reinterpret_cast<const unsigned*>(ws) + OFF_GKEYS;
    float g = dec_f(gk[r*HH + h]);
    for (int blk = 0; blk < 4; ++blk) {
        const float* w1 = reg_w1 + blk*HH*HH;
        const float* w2 = reg_w2 + blk*HH*HH;
        // t1 = relu(g @ w1 + b1)  — broadcast g[hp] via shuffle
        float t1 = reg_b1[blk*HH + h];
        #pragma unroll
        for (int hp = 0; hp < HH; ++hp) t1 += __shfl(g, hp, 64) * w1[hp*HH + h];
        t1 = fmaxf(t1, 0.f);
        // u = t1 @ w2 + b2
        float u = reg_b2[blk*HH + h];
        #pragma unroll
        for (int hp = 0; hp < HH; ++hp) u += __shfl(t1, hp, 64) * w2[hp*HH + h];
        // LayerNorm over the 64 lanes
        float m = u;
        #pragma unroll
        for (int d = 1; d < 64; d <<= 1) m += __shfl_xor(m, d, 64);
        m *= (1.0f/64.0f);
        const float dv = u - m;
        float v = dv * dv;
        #pragma unroll
        for (int d = 1; d < 64; d <<= 1) v += __shfl_xor(v, d, 64);
        v *= (1.0f/64.0f);
        const float y = dv / sqrtf(v + 1e-5f) * reg_ln_g[blk*HH + h] + reg_ln_b[blk*HH + h];
        g += fmaxf(y, 0.f);
    }
    float pr = g * out_w[h];
    #pragma unroll
    for (int d = 1; d < 64; d <<= 1) pr += __shfl_xor(pr, d, 64);
    if (h == 0) out[r] = pr + out_b[0];
}

extern "C" void kernel_launch(void* const* d_in, const int* in_sizes, int n_in,
                              void* d_out, int out_size, void* d_ws, size_t ws_size,
                              hipStream_t stream)
{
    const float* adj     = (const float*)d_in[1];
    const int*   subgs   = (const int*)  d_in[2];
    const float* idemb   = (const float*)d_in[10];
    const float* id_w    = (const float*)d_in[11];
    const float* id_b    = (const float*)d_in[12];
    const float* set1_w  = (const float*)d_in[13];
    const float* set1_b  = (const float*)d_in[14];
    const float* set2_w  = (const float*)d_in[15];
    const float* set2_b  = (const float*)d_in[16];
    const float* reg_w1  = (const float*)d_in[17];
    const float* reg_b1  = (const float*)d_in[18];
    const float* reg_w2  = (const float*)d_in[19];
    const float* reg_b2  = (const float*)d_in[20];
    const float* reg_lng = (const float*)d_in[21];
    const float* reg_lnb = (const float*)d_in[22];
    const float* out_w   = (const float*)d_in[23];
    const float* out_b   = (const float*)d_in[24];
    float* ws  = (float*)d_ws;
    float* out = (float*)d_out;

    hipLaunchKernelGGL(k_prep,  dim3(NB + 1),  dim3(64),   0, stream,
                       adj, idemb, id_w, set1_w, set1_b, ws);
    hipLaunchKernelGGL(k_table, dim3(NCOMBO), dim3(64),   0, stream,
                       id_b, set1_w, ws);
    hipLaunchKernelGGL(k_main,  dim3(NSUB),   dim3(256),  0, stream,
                       adj, subgs, set2_w, set2_b, ws);
    hipLaunchKernelGGL(k_head,  dim3(1),      dim3(1024), 0, stream,
                       reg_w1, reg_b1, reg_w2, reg_b2, reg_lng, reg_lnb,
                       out_w, out_b, ws, out);
}

// Round 2
// 143.642 us; speedup vs baseline: 1.8275x; 1.8275x over previous
//
#include <hip/hip_runtime.h>
#include <math.h>

// Static problem config
#define NB     16      // graphs
#define NN     64      // nodes per graph
#define KK     4       // subgraph size
#define PP     6       // (K-1)!
#define HH     64      // hid dim
#define NSUB   2048    // total subgraphs
#define NC0    65      // c0 in [0,64]
#define NMASK  16      // 2^K
#define NCOMBO (NC0*NMASK)

// Workspace layout (float element offsets)
#define OFF_ROWSUM 0                 // 16*64            = 1024
#define OFF_LABW   1024              // 4*6*64           = 1536
#define OFF_W1SUM  2560              // 64
#define OFF_BASEW  2624              // 5*64             = 320
#define OFF_SW     2944              // 1040*64          = 66560
#define OFF_GKEYS  69504             // 16*64 (as uint)  = 1024

// allperm rows: ap[j][p] for j in 0..3, p in 0..5
__device__ __constant__ int d_ap[4][6] = {
    {0,0,0,0,0,0},{1,1,2,2,3,3},{2,3,1,3,1,2},{3,2,3,1,2,1}};

static __device__ inline float selu_f(float x) {
    const float alpha = 1.6732632423543772f;
    const float scale = 1.0507009873554805f;
    return x > 0.0f ? scale * x : scale * alpha * expm1f(x);
}
// order-preserving float->uint encoding for atomicMax-based segment max
static __device__ inline unsigned enc_f(float x) {
    unsigned b = __float_as_uint(x);
    return (b & 0x80000000u) ? ~b : (b | 0x80000000u);
}
static __device__ inline float dec_f(unsigned k) {
    unsigned b = (k & 0x80000000u) ? (k & 0x7FFFFFFFu) : ~k;
    return __uint_as_float(b);
}

// ---------------- Kernel A: rowsums + small tables + Gkeys init ----------------
// grid: 16 (rowsums) + 1 (scalars/baseW/gk) + 24 (labW, one per (j,p))
__global__ __launch_bounds__(64) void k_prep(
    const float* __restrict__ adj, const float* __restrict__ idemb,
    const float* __restrict__ id_w, const float* __restrict__ set1_w,
    const float* __restrict__ set1_b, float* __restrict__ ws)
{
    const int t = threadIdx.x;            // 0..63
    const int blk = blockIdx.x;
    if (blk < NB) {
        const float4* row = reinterpret_cast<const float4*>(adj + (blk*NN + t)*NN);
        float s = 0.f;
        #pragma unroll
        for (int k = 0; k < 16; ++k) { float4 v = row[k]; s += v.x + v.y + v.z + v.w; }
        ws[OFF_ROWSUM + blk*NN + t] = s;
        return;
    }
    if (blk > NB) {
        // labW[j][p][t] = (lab[j,p,:] @ id_w)[t], lab[j,p,h] = idemb[ap[j][p]][h]*(j+1)*1000
        const int jp = blk - NB - 1;       // 0..23
        const int j = jp / PP, p = jp % PP;
        const float sc = (float)(j+1) * 1000.0f;
        const float* er = idemb + d_ap[j][p]*HH;
        float s = 0.f;
        #pragma unroll
        for (int h = 0; h < HH; ++h) s += (er[h] * sc) * id_w[h*HH + t];
        ws[OFF_LABW + jp*HH + t] = s;
        return;
    }
    // blk == NB: w1sum, baseW, gk init
    float* w1sum = ws + OFF_W1SUM;
    float* baseW = ws + OFF_BASEW;
    unsigned* gk = reinterpret_cast<unsigned*>(ws) + OFF_GKEYS;
    { // w1sum[t] = sum_h id_w[h][t]  (ones-row through id_w)
        float s = 0.f;
        for (int h = 0; h < HH; ++h) s += id_w[h*HH + t];
        w1sum[t] = s;
    }
    // lsum[j][h] = sum_p lab[j,p,h]
    __shared__ float lsum[KK][HH];
    for (int j = 0; j < KK; ++j) {
        const float sc = (float)(j+1) * 1000.0f;
        float s = 0.f;
        for (int p = 0; p < PP; ++p) s += idemb[d_ap[j][p]*HH + t];
        lsum[j][t] = s * sc;
    }
    __syncthreads();
    {
        float cs = 0.f;
        for (int hp = 0; hp < HH; ++hp) cs += set1_w[hp*HH + t];
        baseW[t] = 6.0f * cs + set1_b[t];
        for (int j = 0; j < KK; ++j) {
            float d = 0.f;
            for (int hp = 0; hp < HH; ++hp) d += lsum[j][hp] * set1_w[hp*HH + t];
            baseW[(1+j)*HH + t] = d + set1_b[t];
        }
    }
    for (int i = t; i < NB*HH; i += 64) gk[i] = 0u;  // 0 = smallest key
}

// ---------------- Kernel B: SW[c0,mask,:] table (1040 x 64) ----------------
__global__ __launch_bounds__(64) void k_table(
    const float* __restrict__ id_b, const float* __restrict__ set1_w,
    float* __restrict__ ws)
{
    const int c0   = blockIdx.x >> 4;
    const int mask = blockIdx.x & 15;
    const int t = threadIdx.x;
    const float* labW  = ws + OFF_LABW;
    const float* w1sum = ws + OFF_W1SUM;
    const float fc0 = (float)c0;
    float acc = 0.f;
    #pragma unroll
    for (int p = 0; p < PP; ++p) {
        float arg = fc0 * w1sum[t] + id_b[t];
        #pragma unroll
        for (int j = 0; j < KK; ++j)
            if ((mask >> j) & 1) arg += labW[(j*PP + p)*HH + t];
        acc += selu_f(arg);
    }
    __shared__ float S[HH];
    S[t] = acc;
    __syncthreads();
    float o = 0.f;
    #pragma unroll
    for (int hp = 0; hp < HH; ++hp) o += S[hp] * set1_w[hp*HH + t];
    ws[OFF_SW + blockIdx.x*HH + t] = o;
}

// ---------------- Kernel C: main per-subgraph pass ----------------
__global__ __launch_bounds__(256) void k_main(
    const float* __restrict__ adj, const int* __restrict__ subgs,
    const float* __restrict__ set2_w, const float* __restrict__ set2_b,
    float* __restrict__ ws)
{
    const int s = blockIdx.x;
    const int b = s >> 7;                 // 128 subgraphs per graph
    __shared__ int sub[KK];
    __shared__ float gpart[4][HH];
    if (threadIdx.x < KK) sub[threadIdx.x] = subgs[s*KK + threadIdx.x];
    __syncthreads();
    const int w = threadIdx.x >> 6, h = threadIdx.x & 63;
    const int s0 = sub[0], s1 = sub[1], s2 = sub[2], s3 = sub[3];
    const float* adjb = adj + b*NN*NN;
    const float* rs   = ws + OFF_ROWSUM + b*NN;
    const float* SW   = ws + OFF_SW;
    const float* baseW= ws + OFF_BASEW;
    float facc = 0.f;
    #pragma unroll 4
    for (int it = 0; it < 16; ++it) {
        const int i = w*16 + it;
        const float* arow = adjb + i*NN;
        const float a0 = arow[s0], a1 = arow[s1], a2 = arow[s2], a3 = arow[s3];
        const float c0f = rs[i] - (a0 + a1 + a2 + a3);
        const int ic0 = (int)(c0f + 0.5f);           // exact small integer
        const int mask = (a0 != 0.f ? 1 : 0) | (a1 != 0.f ? 2 : 0)
                       | (a2 != 0.f ? 4 : 0) | (a3 != 0.f ? 8 : 0);
        const int var = (i==s0) ? 1 : (i==s1) ? 2 : (i==s2) ? 3 : (i==s3) ? 4 : 0;
        const float val = SW[(ic0*NMASK + mask)*HH + h] + baseW[var*HH + h];
        facc += selu_f(val);
    }
    gpart[w][h] = facc;
    __syncthreads();
    if (w == 0) gpart[0][h] = gpart[0][h] + gpart[1][h] + gpart[2][h] + gpart[3][h];
    __syncthreads();                       // all 4 waves participate
    if (w == 0) {
        // matvec with LDS-broadcast reads (same ascending-hp order as before)
        float o = set2_b[h];
        #pragma unroll
        for (int hp = 0; hp < HH; ++hp)
            o += gpart[0][hp] * set2_w[hp*HH + h];
        const float gq = selu_f(o);
        unsigned* gk = reinterpret_cast<unsigned*>(ws) + OFF_GKEYS;
        atomicMax(gk + b*HH + h, enc_f(gq));
    }
}

// ---------------- Kernel D: head — one block (CU) per graph row ----------------
// 4 waves stage reg_w1+reg_w2 (128 KiB) into LDS with float4 loads (wide miss
// window across 16 CUs); wave 0 then runs the 4 residual MLP blocks with
// LDS-broadcast matvecs. Same FP order as reference.
__global__ __launch_bounds__(256) void k_head(
    const float* __restrict__ reg_w1, const float* __restrict__ reg_b1,
    const float* __restrict__ reg_w2, const float* __restrict__ reg_b2,
    const float* __restrict__ reg_ln_g, const float* __restrict__ reg_ln_b,
    const float* __restrict__ out_w, const float* __restrict__ out_b,
    const float* __restrict__ ws, float* __restrict__ out)
{
    __shared__ float swgt[2*KK*HH*HH];     // [0..16383]=w1 all blocks, [16384..]=w2
    __shared__ float gs[HH];
    const int tid = threadIdx.x;
    {   // cooperative staging: 8192 float4s over 256 threads = 32 iters
        const float4* g1 = reinterpret_cast<const float4*>(reg_w1);
        const float4* g2 = reinterpret_cast<const float4*>(reg_w2);
        float4* s4 = reinterpret_cast<float4*>(swgt);
        #pragma unroll
        for (int i = 0; i < 16; ++i) s4[i*256 + tid] = g1[i*256 + tid];
        #pragma unroll
        for (int i = 0; i < 16; ++i) s4[4096 + i*256 + tid] = g2[i*256 + tid];
    }
    __syncthreads();
    if (tid >= 64) return;                 // wave 0 computes; others done
    const int r = blockIdx.x;              // graph row
    const int h = tid;
    const unsigned* gk = reinterpret_cast<const unsigned*>(ws) + OFF_GKEYS;
    float g = dec_f(gk[r*HH + h]);
    for (int blk = 0; blk < 4; ++blk) {
        const float* w1 = swgt + blk*HH*HH;
        const float* w2 = swgt + KK*HH*HH + blk*HH*HH;
        gs[h] = g;
        __syncthreads();
        float t1 = reg_b1[blk*HH + h];
        #pragma unroll
        for (int hp = 0; hp < HH; ++hp) t1 += gs[hp] * w1[hp*HH + h];
        t1 = fmaxf(t1, 0.f);
        gs[h] = t1;                        // reuse gs: all lanes past reads (single wave)
        __syncthreads();
        float u = reg_b2[blk*HH + h];
        #pragma unroll
        for (int hp = 0; hp < HH; ++hp) u += gs[hp] * w2[hp*HH + h];
        __syncthreads();
        // LayerNorm over the 64 lanes (same butterfly order as before)
        float m = u;
        #pragma unroll
        for (int d = 1; d < 64; d <<= 1) m += __shfl_xor(m, d, 64);
        m *= (1.0f/64.0f);
        const float dv = u - m;
        float v = dv * dv;
        #pragma unroll
        for (int d = 1; d < 64; d <<= 1) v += __shfl_xor(v, d, 64);
        v *= (1.0f/64.0f);
        const float y = dv / sqrtf(v + 1e-5f) * reg_ln_g[blk*HH + h] + reg_ln_b[blk*HH + h];
        g += fmaxf(y, 0.f);
    }
    float pr = g * out_w[h];
    #pragma unroll
    for (int d = 1; d < 64; d <<= 1) pr += __shfl_xor(pr, d, 64);
    if (h == 0) out[r] = pr + out_b[0];
}

extern "C" void kernel_launch(void* const* d_in, const int* in_sizes, int n_in,
                              void* d_out, int out_size, void* d_ws, size_t ws_size,
                              hipStream_t stream)
{
    const float* adj     = (const float*)d_in[1];
    const int*   subgs   = (const int*)  d_in[2];
    const float* idemb   = (const float*)d_in[10];
    const float* id_w    = (const float*)d_in[11];
    const float* id_b    = (const float*)d_in[12];
    const float* set1_w  = (const float*)d_in[13];
    const float* set1_b  = (const float*)d_in[14];
    const float* set2_w  = (const float*)d_in[15];
    const float* set2_b  = (const float*)d_in[16];
    const float* reg_w1  = (const float*)d_in[17];
    const float* reg_b1  = (const float*)d_in[18];
    const float* reg_w2  = (const float*)d_in[19];
    const float* reg_b2  = (const float*)d_in[20];
    const float* reg_lng = (const float*)d_in[21];
    const float* reg_lnb = (const float*)d_in[22];
    const float* out_w   = (const float*)d_in[23];
    const float* out_b   = (const float*)d_in[24];
    float* ws  = (float*)d_ws;
    float* out = (float*)d_out;

    hipLaunchKernelGGL(k_prep,  dim3(NB + 1 + KK*PP), dim3(64),  0, stream,
                       adj, idemb, id_w, set1_w, set1_b, ws);
    hipLaunchKernelGGL(k_table, dim3(NCOMBO), dim3(64),   0, stream,
                       id_b, set1_w, ws);
    hipLaunchKernelGGL(k_main,  dim3(NSUB),   dim3(256),  0, stream,
                       adj, subgs, set2_w, set2_b, ws);
    hipLaunchKernelGGL(k_head,  dim3(NB),     dim3(256),  0, stream,
                       reg_w1, reg_b1, reg_w2, reg_b2, reg_lng, reg_lnb,
                       out_w, out_b, ws, out);
}

// Round 3
// 140.104 us; speedup vs baseline: 1.8736x; 1.0253x over previous
//
#include <hip/hip_runtime.h>
#include <math.h>

// Static problem config
#define NB     16      // graphs
#define NN     64      // nodes per graph
#define KK     4       // subgraph size
#define PP     6       // (K-1)!
#define HH     64      // hid dim
#define NSUB   2048    // total subgraphs
#define NC0    65      // c0 in [0,64]
#define NMASK  16      // 2^K
#define NCOMBO (NC0*NMASK)
#define NVAR   5       // var = 0 (not in subg) or 1+j (i == subgs[j])

// Workspace layout (float element offsets)
#define OFF_ROWSUM 0                 // 16*64             = 1024
#define OFF_LABW   1024              // 4*6*64            = 1536
#define OFF_W1SUM  2560              // 64
#define OFF_BASEW  2624              // 5*64              = 320
#define OFF_T2     2944              // 5*1040*64         = 332800
#define OFF_GKEYS  335744            // 16*64 (as uint)   = 1024
// total ~1.35 MB of the 256 MB workspace

// allperm rows: ap[j][p] for j in 0..3, p in 0..5
__device__ __constant__ int d_ap[4][6] = {
    {0,0,0,0,0,0},{1,1,2,2,3,3},{2,3,1,3,1,2},{3,2,3,1,2,1}};

static __device__ inline float selu_f(float x) {
    const float alpha = 1.6732632423543772f;
    const float scale = 1.0507009873554805f;
    return x > 0.0f ? scale * x : scale * alpha * expm1f(x);
}
// order-preserving float->uint encoding for atomicMax-based segment max
static __device__ inline unsigned enc_f(float x) {
    unsigned b = __float_as_uint(x);
    return (b & 0x80000000u) ? ~b : (b | 0x80000000u);
}
static __device__ inline float dec_f(unsigned k) {
    unsigned b = (k & 0x80000000u) ? (k & 0x7FFFFFFFu) : ~k;
    return __uint_as_float(b);
}

// ---------------- Kernel A: rowsums + small tables + Gkeys init ----------------
// grid: 16 (rowsums) + 1 (scalars/baseW/gk) + 24 (labW, one per (j,p))
__global__ __launch_bounds__(64) void k_prep(
    const float* __restrict__ adj, const float* __restrict__ idemb,
    const float* __restrict__ id_w, const float* __restrict__ set1_w,
    const float* __restrict__ set1_b, float* __restrict__ ws)
{
    const int t = threadIdx.x;            // 0..63
    const int blk = blockIdx.x;
    if (blk < NB) {
        const float4* row = reinterpret_cast<const float4*>(adj + (blk*NN + t)*NN);
        float s = 0.f;
        #pragma unroll
        for (int k = 0; k < 16; ++k) { float4 v = row[k]; s += v.x + v.y + v.z + v.w; }
        ws[OFF_ROWSUM + blk*NN + t] = s;
        return;
    }
    if (blk > NB) {
        // labW[j][p][t] = (lab[j,p,:] @ id_w)[t], lab[j,p,h] = idemb[ap[j][p]][h]*(j+1)*1000
        const int jp = blk - NB - 1;       // 0..23
        const int j = jp / PP, p = jp % PP;
        const float sc = (float)(j+1) * 1000.0f;
        const float* er = idemb + d_ap[j][p]*HH;
        float s = 0.f;
        #pragma unroll
        for (int h = 0; h < HH; ++h) s += (er[h] * sc) * id_w[h*HH + t];
        ws[OFF_LABW + jp*HH + t] = s;
        return;
    }
    // blk == NB: w1sum, baseW, gk init
    float* w1sum = ws + OFF_W1SUM;
    float* baseW = ws + OFF_BASEW;
    unsigned* gk = reinterpret_cast<unsigned*>(ws) + OFF_GKEYS;
    { // w1sum[t] = sum_h id_w[h][t]  (ones-row through id_w)
        float s = 0.f;
        for (int h = 0; h < HH; ++h) s += id_w[h*HH + t];
        w1sum[t] = s;
    }
    // lsum[j][h] = sum_p lab[j,p,h]
    __shared__ float lsum[KK][HH];
    for (int j = 0; j < KK; ++j) {
        const float sc = (float)(j+1) * 1000.0f;
        float s = 0.f;
        for (int p = 0; p < PP; ++p) s += idemb[d_ap[j][p]*HH + t];
        lsum[j][t] = s * sc;
    }
    __syncthreads();
    {
        float cs = 0.f;
        for (int hp = 0; hp < HH; ++hp) cs += set1_w[hp*HH + t];
        baseW[t] = 6.0f * cs + set1_b[t];
        for (int j = 0; j < KK; ++j) {
            float d = 0.f;
            for (int hp = 0; hp < HH; ++hp) d += lsum[j][hp] * set1_w[hp*HH + t];
            baseW[(1+j)*HH + t] = d + set1_b[t];
        }
    }
    for (int i = t; i < NB*HH; i += 64) gk[i] = 0u;  // 0 = smallest key
}

// ---------------- Kernel B: T2[var][c0][mask][h] = selu(SW + baseW[var]) ------
// one block per (c0,mask); SW kept in registers/LDS, 5 selu'd variant rows out.
__global__ __launch_bounds__(64) void k_table(
    const float* __restrict__ id_b, const float* __restrict__ set1_w,
    float* __restrict__ ws)
{
    const int c0   = blockIdx.x >> 4;
    const int mask = blockIdx.x & 15;
    const int t = threadIdx.x;
    const float* labW  = ws + OFF_LABW;
    const float* w1sum = ws + OFF_W1SUM;
    const float* baseW = ws + OFF_BASEW;
    const float fc0 = (float)c0;
    float acc = 0.f;
    #pragma unroll
    for (int p = 0; p < PP; ++p) {
        float arg = fc0 * w1sum[t] + id_b[t];
        #pragma unroll
        for (int j = 0; j < KK; ++j)
            if ((mask >> j) & 1) arg += labW[(j*PP + p)*HH + t];
        acc += selu_f(arg);
    }
    __shared__ float S[HH];
    S[t] = acc;
    __syncthreads();
    float o = 0.f;
    #pragma unroll
    for (int hp = 0; hp < HH; ++hp) o += S[hp] * set1_w[hp*HH + t];
    #pragma unroll
    for (int var = 0; var < NVAR; ++var)
        ws[OFF_T2 + (var*NCOMBO + blockIdx.x)*HH + t] = selu_f(o + baseW[var*HH + t]);
}

// ---------------- Kernel C: main per-subgraph pass (pure table-gather) --------
__global__ __launch_bounds__(256) void k_main(
    const float* __restrict__ adj, const int* __restrict__ subgs,
    const float* __restrict__ set2_w, const float* __restrict__ set2_b,
    float* __restrict__ ws)
{
    const int s = blockIdx.x;
    const int b = s >> 7;                 // 128 subgraphs per graph
    __shared__ int sub[KK];
    __shared__ float gpart[4][HH];
    if (threadIdx.x < KK) sub[threadIdx.x] = subgs[s*KK + threadIdx.x];
    __syncthreads();
    const int w = threadIdx.x >> 6, h = threadIdx.x & 63;
    const int s0 = sub[0], s1 = sub[1], s2 = sub[2], s3 = sub[3];
    const float* adjb = adj + b*NN*NN;
    const float* rs   = ws + OFF_ROWSUM + b*NN;
    const float* T2   = ws + OFF_T2;
    float facc = 0.f;
    #pragma unroll 4
    for (int it = 0; it < 16; ++it) {
        const int i = w*16 + it;
        const float* arow = adjb + i*NN;
        const float a0 = arow[s0], a1 = arow[s1], a2 = arow[s2], a3 = arow[s3];
        const float c0f = rs[i] - (a0 + a1 + a2 + a3);
        const int ic0 = (int)(c0f + 0.5f);           // exact small integer
        const int mask = (a0 != 0.f ? 1 : 0) | (a1 != 0.f ? 2 : 0)
                       | (a2 != 0.f ? 4 : 0) | (a3 != 0.f ? 8 : 0);
        const int var = (i==s0) ? 1 : (i==s1) ? 2 : (i==s2) ? 3 : (i==s3) ? 4 : 0;
        facc += T2[(var*NCOMBO + ic0*NMASK + mask)*HH + h];
    }
    gpart[w][h] = facc;
    __syncthreads();
    if (w == 0) gpart[0][h] = gpart[0][h] + gpart[1][h] + gpart[2][h] + gpart[3][h];
    __syncthreads();                       // all 4 waves participate
    if (w == 0) {
        float o = set2_b[h];
        #pragma unroll
        for (int hp = 0; hp < HH; ++hp)
            o += gpart[0][hp] * set2_w[hp*HH + h];
        const float gq = selu_f(o);
        unsigned* gk = reinterpret_cast<unsigned*>(ws) + OFF_GKEYS;
        atomicMax(gk + b*HH + h, enc_f(gq));
    }
}

// ---------------- Kernel D: head — one block (CU) per graph row ----------------
__global__ __launch_bounds__(256) void k_head(
    const float* __restrict__ reg_w1, const float* __restrict__ reg_b1,
    const float* __restrict__ reg_w2, const float* __restrict__ reg_b2,
    const float* __restrict__ reg_ln_g, const float* __restrict__ reg_ln_b,
    const float* __restrict__ out_w, const float* __restrict__ out_b,
    const float* __restrict__ ws, float* __restrict__ out)
{
    __shared__ float swgt[2*KK*HH*HH];     // [0..16383]=w1 all blocks, [16384..]=w2
    __shared__ float gs[HH];
    const int tid = threadIdx.x;
    {   // cooperative staging: 8192 float4s over 256 threads = 32 iters
        const float4* g1 = reinterpret_cast<const float4*>(reg_w1);
        const float4* g2 = reinterpret_cast<const float4*>(reg_w2);
        float4* s4 = reinterpret_cast<float4*>(swgt);
        #pragma unroll
        for (int i = 0; i < 16; ++i) s4[i*256 + tid] = g1[i*256 + tid];
        #pragma unroll
        for (int i = 0; i < 16; ++i) s4[4096 + i*256 + tid] = g2[i*256 + tid];
    }
    __syncthreads();
    if (tid >= 64) return;                 // wave 0 computes; others done
    const int r = blockIdx.x;              // graph row
    const int h = tid;
    const unsigned* gk = reinterpret_cast<const unsigned*>(ws) + OFF_GKEYS;
    float g = dec_f(gk[r*HH + h]);
    for (int blk = 0; blk < 4; ++blk) {
        const float* w1 = swgt + blk*HH*HH;
        const float* w2 = swgt + KK*HH*HH + blk*HH*HH;
        gs[h] = g;
        __syncthreads();
        float t1 = reg_b1[blk*HH + h];
        #pragma unroll
        for (int hp = 0; hp < HH; ++hp) t1 += gs[hp] * w1[hp*HH + h];
        t1 = fmaxf(t1, 0.f);
        gs[h] = t1;                        // single wave: prior reads complete
        __syncthreads();
        float u = reg_b2[blk*HH + h];
        #pragma unroll
        for (int hp = 0; hp < HH; ++hp) u += gs[hp] * w2[hp*HH + h];
        __syncthreads();
        // LayerNorm over the 64 lanes
        float m = u;
        #pragma unroll
        for (int d = 1; d < 64; d <<= 1) m += __shfl_xor(m, d, 64);
        m *= (1.0f/64.0f);
        const float dv = u - m;
        float v = dv * dv;
        #pragma unroll
        for (int d = 1; d < 64; d <<= 1) v += __shfl_xor(v, d, 64);
        v *= (1.0f/64.0f);
        const float y = dv / sqrtf(v + 1e-5f) * reg_ln_g[blk*HH + h] + reg_ln_b[blk*HH + h];
        g += fmaxf(y, 0.f);
    }
    float pr = g * out_w[h];
    #pragma unroll
    for (int d = 1; d < 64; d <<= 1) pr += __shfl_xor(pr, d, 64);
    if (h == 0) out[r] = pr + out_b[0];
}

extern "C" void kernel_launch(void* const* d_in, const int* in_sizes, int n_in,
                              void* d_out, int out_size, void* d_ws, size_t ws_size,
                              hipStream_t stream)
{
    const float* adj     = (const float*)d_in[1];
    const int*   subgs   = (const int*)  d_in[2];
    const float* idemb   = (const float*)d_in[10];
    const float* id_w    = (const float*)d_in[11];
    const float* id_b    = (const float*)d_in[12];
    const float* set1_w  = (const float*)d_in[13];
    const float* set1_b  = (const float*)d_in[14];
    const float* set2_w  = (const float*)d_in[15];
    const float* set2_b  = (const float*)d_in[16];
    const float* reg_w1  = (const float*)d_in[17];
    const float* reg_b1  = (const float*)d_in[18];
    const float* reg_w2  = (const float*)d_in[19];
    const float* reg_b2  = (const float*)d_in[20];
    const float* reg_lng = (const float*)d_in[21];
    const float* reg_lnb = (const float*)d_in[22];
    const float* out_w   = (const float*)d_in[23];
    const float* out_b   = (const float*)d_in[24];
    float* ws  = (float*)d_ws;
    float* out = (float*)d_out;

    hipLaunchKernelGGL(k_prep,  dim3(NB + 1 + KK*PP), dim3(64),  0, stream,
                       adj, idemb, id_w, set1_w, set1_b, ws);
    hipLaunchKernelGGL(k_table, dim3(NCOMBO), dim3(64),   0, stream,
                       id_b, set1_w, ws);
    hipLaunchKernelGGL(k_main,  dim3(NSUB),   dim3(256),  0, stream,
                       adj, subgs, set2_w, set2_b, ws);
    hipLaunchKernelGGL(k_head,  dim3(NB),     dim3(256),  0, stream,
                       reg_w1, reg_b1, reg_w2, reg_b2, reg_lng, reg_lnb,
                       out_w, out_b, ws, out);
}